// Round 3
// baseline (12752.154 us; speedup 1.0000x reference)
//
#include <hip/hip_runtime.h>
#include <math.h>
#include <stdint.h>

#define B_   32
#define TI_  128
#define TO_  64
#define E_   256
#define H_   512
#define A_   512
#define VO_  32000
#define G3_  1536   // 3H
#define D2H_ 1024   // 2H

using short8 = __attribute__((ext_vector_type(8))) short;
using f32x4  = __attribute__((ext_vector_type(4))) float;

__device__ __forceinline__ unsigned short f2bf(float x) {
  uint32_t u = __builtin_bit_cast(uint32_t, x);
  uint32_t r = (u + 0x7fffu + ((u >> 16) & 1u)) >> 16;
  return (unsigned short)r;
}

// ---- device-scope grid barrier (all blocks resident; monotonic counter) ----
__device__ __forceinline__ void gbar(int* bar, int target) {
  __syncthreads();                    // drains vmcnt -> block's stores in L2
  if (threadIdx.x == 0) {
    __threadfence();                  // agent release: L2 writeback
    atomicAdd(bar, 1);
    while (__hip_atomic_load(bar, __ATOMIC_RELAXED, __HIP_MEMORY_SCOPE_AGENT) < target)
      __builtin_amdgcn_s_sleep(4);
    __threadfence();                  // agent acquire: L1/L2 invalidate
  }
  __syncthreads();
}

// ---------------- init: zero h0 buffers, HA tail rows, barrier counters -----
__global__ __launch_bounds__(256) void k_init(float* __restrict__ hf0,
                                              float* __restrict__ hb0,
                                              unsigned short* __restrict__ HAtail,
                                              int* __restrict__ bar) {
  int i = blockIdx.x * 256 + threadIdx.x;
  if (i < B_ * H_) { hf0[i] = 0.f; hb0[i] = 0.f; }
  if (i < 32 * G3_) HAtail[i] = 0;
  if (i < 2) bar[i] = 0;
}

// f32 -> bf16, 8 elements per thread
__global__ __launch_bounds__(256) void k_cvt_bf16(const float* __restrict__ in,
                                                  unsigned short* __restrict__ out, int n8) {
  int i = blockIdx.x * 256 + threadIdx.x;
  if (i >= n8) return;
  float4 a = ((const float4*)in)[2 * i];
  float4 b = ((const float4*)in)[2 * i + 1];
  ((ushort4*)out)[2 * i]     = make_ushort4(f2bf(a.x), f2bf(a.y), f2bf(a.z), f2bf(a.w));
  ((ushort4*)out)[2 * i + 1] = make_ushort4(f2bf(b.x), f2bf(b.y), f2bf(b.z), f2bf(b.w));
}

__global__ __launch_bounds__(256) void k_gather_x(const int* __restrict__ inp,
                                                  const float* __restrict__ emb,
                                                  float* __restrict__ x) {
  int idx = blockIdx.x * 256 + threadIdx.x;
  int total = B_ * TI_ * E_ / 4;
  if (idx >= total) return;
  int row = idx / (E_ / 4);
  int e4  = idx % (E_ / 4);
  int tok = inp[row];
  ((float4*)x)[idx] = ((const float4*)emb)[(size_t)tok * (E_ / 4) + e4];
}

__global__ __launch_bounds__(256) void k_gather_xe(const int* __restrict__ outidx,
                                                   const float* __restrict__ emb,
                                                   float* __restrict__ xe) {
  int idx = blockIdx.x * 256 + threadIdx.x;
  int total = 63 * B_ * E_ / 4;
  if (idx >= total) return;
  int row = idx / (E_ / 4);
  int e4  = idx % (E_ / 4);
  int i = row / B_, b = row % B_;
  int tok = outidx[b * TO_ + i];
  ((float4*)xe)[idx] = ((const float4*)emb)[(size_t)tok * (E_ / 4) + e4];
}

__global__ __launch_bounds__(256) void k_first(float* __restrict__ dout) {
  int idx = blockIdx.x * 256 + threadIdx.x;
  if (idx >= B_ * VO_) return;
  int b = idx / VO_, v = idx % VO_;
  dout[(size_t)b * TO_ * VO_ + v] = (v == 1) ? 0.f : -20.72326583694641f;
}

// ---------------- generic f32 GEMM: C[M,N] = A[M,lda-K] @ W[N,ldw]^T + bias ----
__global__ __launch_bounds__(256) void k_gemm128(
    const float* __restrict__ A, int lda,
    const float* __restrict__ W, int ldw,
    const float* __restrict__ bias,
    float* __restrict__ C, int M, int N, int K) {
  __shared__ float As[32][132];
  __shared__ float Bs[32][132];
  const int tid = threadIdx.x;
  const int m0 = blockIdx.y * 128, n0 = blockIdx.x * 128;
  const int tx = tid & 15, ty = tid >> 4;
  float acc[8][8];
#pragma unroll
  for (int i = 0; i < 8; ++i)
#pragma unroll
    for (int j = 0; j < 8; ++j) acc[i][j] = 0.f;

  for (int k0 = 0; k0 < K; k0 += 32) {
#pragma unroll
    for (int i = 0; i < 16; ++i) {
      int idx = tid + i * 256;
      int kk = idx & 31, mm = idx >> 5;
      int m = m0 + mm;
      As[kk][mm] = (m < M) ? A[(size_t)m * lda + k0 + kk] : 0.f;
      Bs[kk][mm] = W[(size_t)(n0 + mm) * ldw + k0 + kk];
    }
    __syncthreads();
#pragma unroll
    for (int kk = 0; kk < 32; ++kk) {
      float4 a0 = *(const float4*)&As[kk][ty * 8];
      float4 a1 = *(const float4*)&As[kk][ty * 8 + 4];
      float4 b0 = *(const float4*)&Bs[kk][tx * 8];
      float4 b1 = *(const float4*)&Bs[kk][tx * 8 + 4];
      float av[8] = {a0.x, a0.y, a0.z, a0.w, a1.x, a1.y, a1.z, a1.w};
      float bv[8] = {b0.x, b0.y, b0.z, b0.w, b1.x, b1.y, b1.z, b1.w};
#pragma unroll
      for (int i = 0; i < 8; ++i)
#pragma unroll
        for (int j = 0; j < 8; ++j) acc[i][j] = fmaf(av[i], bv[j], acc[i][j]);
    }
    __syncthreads();
  }

#pragma unroll
  for (int i = 0; i < 8; ++i) {
    int m = m0 + ty * 8 + i;
    if (m >= M) continue;
#pragma unroll
    for (int j = 0; j < 8; ++j) {
      int n = n0 + tx * 8 + j;
      C[(size_t)m * N + n] = acc[i][j] + bias[n];
    }
  }
}

// ---------------- bf16 MFMA logits GEMM (m97 structure) ----------------------
__global__ __launch_bounds__(256) void k_logits_mfma(
    const unsigned short* __restrict__ A,
    const unsigned short* __restrict__ Bt,
    const float* __restrict__ bias,
    float* __restrict__ out) {
  __shared__ alignas(16) unsigned short As[128 * 32];
  __shared__ alignas(16) unsigned short Bs[128 * 32];
  const int tid = threadIdx.x;
  const int wave = tid >> 6, lane = tid & 63;
  const int m0 = blockIdx.y * 128, n0 = blockIdx.x * 128;
  const int wr = wave >> 1, wc = wave & 1;
  const int K = G3_;

  f32x4 acc[4][4];
#pragma unroll
  for (int i = 0; i < 4; ++i)
#pragma unroll
    for (int j = 0; j < 4; ++j) acc[i][j] = (f32x4){0.f, 0.f, 0.f, 0.f};

  const int srow = tid >> 2;
  const int sbyte = (tid & 3) * 16;
  const int fr = lane & 15;
  const int fkb = (lane >> 4) * 16;

  for (int k0 = 0; k0 < K; k0 += 32) {
#pragma unroll
    for (int rd = 0; rd < 2; ++rd) {
      int row = rd * 64 + srow;
      const char* ga = (const char*)(A + (size_t)(m0 + row) * K + k0) + sbyte;
      const char* gb = (const char*)(Bt + (size_t)(n0 + row) * K + k0) + sbyte;
      __builtin_amdgcn_global_load_lds(
          (const __attribute__((address_space(1))) uint32_t*)ga,
          (__attribute__((address_space(3))) uint32_t*)((char*)As + rd * 4096 + wave * 1024),
          16, 0, 0);
      __builtin_amdgcn_global_load_lds(
          (const __attribute__((address_space(1))) uint32_t*)gb,
          (__attribute__((address_space(3))) uint32_t*)((char*)Bs + rd * 4096 + wave * 1024),
          16, 0, 0);
    }
    __syncthreads();

    short8 af[4], bf[4];
#pragma unroll
    for (int i = 0; i < 4; ++i) {
      int ar = wr * 64 + i * 16 + fr;
      int bc = wc * 64 + i * 16 + fr;
      af[i] = *(const short8*)((const char*)As + ar * 64 + fkb);
      bf[i] = *(const short8*)((const char*)Bs + bc * 64 + fkb);
    }
#pragma unroll
    for (int i = 0; i < 4; ++i)
#pragma unroll
      for (int j = 0; j < 4; ++j)
        acc[i][j] = __builtin_amdgcn_mfma_f32_16x16x32_bf16(af[i], bf[j], acc[i][j], 0, 0, 0);
    __syncthreads();
  }

  const int crow = (lane >> 4) * 4, ccol = lane & 15;
#pragma unroll
  for (int i = 0; i < 4; ++i) {
#pragma unroll
    for (int r = 0; r < 4; ++r) {
      int m = m0 + wr * 64 + i * 16 + crow + r;
      if (m >= 63 * B_) continue;
      int b = m & 31, st = m >> 5;
      float* orow = out + ((size_t)b * TO_ + st + 1) * VO_;
#pragma unroll
      for (int j = 0; j < 4; ++j) {
        int n = n0 + wc * 64 + j * 16 + ccol;
        orow[n] = acc[i][j][r] + bias[n];
      }
    }
  }
}

// ---------------- persistent encoder: all 128 steps, both directions ---------
// 128 blocks: dir = bid>>6, slice = bid&63 (8 h-cols). 127 grid barriers.

__global__ __launch_bounds__(256) void k_encoder(
    const float* __restrict__ xp_f, const float* __restrict__ xp_b,
    const float* __restrict__ Whh_f, const float* __restrict__ bhh_f,
    const float* __restrict__ Whh_b, const float* __restrict__ bhh_b,
    float* __restrict__ hf0, float* __restrict__ hf1,
    float* __restrict__ hb0, float* __restrict__ hb1,
    float* __restrict__ enc, int* __restrict__ bar) {
  __shared__ float hs[32 * 516];
  const int bid = blockIdx.x;
  const int dir = bid >> 6, slice = bid & 63;
  const float* xp  = dir ? xp_b : xp_f;
  const float* Whh = dir ? Whh_b : Whh_f;
  const float* bhh = dir ? bhh_b : bhh_f;
  float* hp0 = dir ? hb0 : hf0;
  float* hp1 = dir ? hb1 : hf1;
  const int tid = threadIdx.x;
  const int m = tid & 31, c = tid >> 5;
  const int col = slice * 8 + c;
  const float* hrow = hs + m * 516;
  const float4* wr = (const float4*)(Whh + (size_t)col * H_);
  const float4* wz = (const float4*)(Whh + (size_t)(H_ + col) * H_);
  const float4* wn = (const float4*)(Whh + (size_t)(2 * H_ + col) * H_);
  const float br = bhh[col], bz = bhh[512 + col], bn = bhh[1024 + col];

  for (int t = 0; t < TI_; ++t) {
    const float* h_in = (t & 1) ? hp1 : hp0;
    float*       h_out = (t & 1) ? hp0 : hp1;
    const int tt = dir ? (TI_ - 1 - t) : t;

#pragma unroll
    for (int i = 0; i < 16; ++i) {
      int flat = (tid + i * 256) * 4;
      int mm = flat >> 9, kk = flat & 511;
      *(float4*)&hs[mm * 516 + kk] = *(const float4*)(h_in + (size_t)mm * H_ + kk);
    }
    __syncthreads();

    float accr = 0.f, accz = 0.f, accn = 0.f;
#pragma unroll 4
    for (int k4 = 0; k4 < H_ / 4; ++k4) {
      float4 h4 = *(const float4*)(hrow + k4 * 4);
      float4 r = wr[k4], z = wz[k4], n = wn[k4];
      accr = fmaf(h4.x, r.x, fmaf(h4.y, r.y, fmaf(h4.z, r.z, fmaf(h4.w, r.w, accr))));
      accz = fmaf(h4.x, z.x, fmaf(h4.y, z.y, fmaf(h4.z, z.z, fmaf(h4.w, z.w, accz))));
      accn = fmaf(h4.x, n.x, fmaf(h4.y, n.y, fmaf(h4.z, n.z, fmaf(h4.w, n.w, accn))));
    }
    size_t xoff = ((size_t)m * TI_ + tt) * G3_ + col;
    float xr = xp[xoff], xz = xp[xoff + 512], xn = xp[xoff + 1024];
    float r = 1.f / (1.f + expf(-(xr + accr + br)));
    float z = 1.f / (1.f + expf(-(xz + accz + bz)));
    float nn = tanhf(xn + accn + bn + r * 0.f + r * (accn * 0.f) + r * 0.f + (accn + bn) * 0.f + r * ((accn + bn) - (accn + bn)) + r * (accn + bn) - r * (accn + bn));
    // NOTE: keep exact semantics: n = tanh(xn + r*hn), hn = accn + bn
    nn = tanhf(xn + r * (accn + bn));
    float hold = hrow[col];
    float hnew = (1.f - z) * nn + z * hold;
    h_out[m * H_ + col] = hnew;
    enc[((size_t)m * TI_ + tt) * D2H_ + dir * H_ + col] = hnew;

    if (t < TI_ - 1) gbar(bar, 128 * (t + 1));
  }
}

// ---------------- decoder bodies ---------------------------------------------

__device__ void attend_body(int b, int tid,
                            const float* __restrict__ h_src, const float* __restrict__ enc,
                            const float* __restrict__ encp, const int* __restrict__ inp,
                            const float* __restrict__ Wdec, const float* __restrict__ bdec,
                            const float* __restrict__ v, const float* __restrict__ vb,
                            float* __restrict__ a_out, unsigned short* __restrict__ HA, int step,
                            float* hq, float* dp, float* vv, float* part, float* sc, float* red) {
  hq[tid] = h_src[b * H_ + tid];
  hq[tid + 256] = h_src[b * H_ + 256 + tid];
  vv[tid] = v[tid];
  vv[tid + 256] = v[tid + 256];
  __syncthreads();

#pragma unroll
  for (int jj = 0; jj < 2; ++jj) {
    int j = tid + jj * 256;
    const float4* w4 = (const float4*)(Wdec + (size_t)j * H_);
    float acc = 0.f;
#pragma unroll 4
    for (int k4 = 0; k4 < H_ / 4; ++k4) {
      float4 w = w4[k4];
      float4 h4 = *(const float4*)&hq[k4 * 4];
      acc = fmaf(h4.x, w.x, fmaf(h4.y, w.y, fmaf(h4.z, w.z, fmaf(h4.w, w.w, acc))));
    }
    dp[j] = acc + bdec[j];
  }
  __syncthreads();

  {
    int t = tid & 127, half = tid >> 7;
    const float* ep = encp + ((size_t)b * TI_ + t) * A_ + half * 256;
    const float* dph = dp + half * 256;
    const float* vh = vv + half * 256;
    float p = 0.f;
    for (int a = 0; a < 256; ++a) p = fmaf(vh[a], tanhf(ep[a] + dph[a]), p);
    part[tid] = p;
  }
  __syncthreads();
  if (tid < 128) {
    float s = part[tid] + part[tid + 128] + vb[0];
    if (inp[b * TI_ + tid] == 0) s = -INFINITY;
    sc[tid] = s;
    red[tid] = s;
  }
  __syncthreads();
  for (int o = 64; o > 0; o >>= 1) {
    if (tid < o) red[tid] = fmaxf(red[tid], red[tid + o]);
    __syncthreads();
  }
  float mx = red[0];
  __syncthreads();
  if (tid < 128) {
    float e = expf(sc[tid] - mx);
    sc[tid] = e;
    red[tid] = e;
  }
  __syncthreads();
  for (int o = 64; o > 0; o >>= 1) {
    if (tid < o) red[tid] += red[tid + o];
    __syncthreads();
  }
  float inv = 1.f / red[0];
  __syncthreads();

  float4 acc = make_float4(0.f, 0.f, 0.f, 0.f);
  const float4* e4p = (const float4*)(enc + (size_t)b * TI_ * D2H_) + tid;
#pragma unroll 4
  for (int t2 = 0; t2 < TI_; ++t2) {
    float pr = sc[t2] * inv;
    float4 ev = e4p[(size_t)t2 * (D2H_ / 4)];
    acc.x = fmaf(pr, ev.x, acc.x);
    acc.y = fmaf(pr, ev.y, acc.y);
    acc.z = fmaf(pr, ev.z, acc.z);
    acc.w = fmaf(pr, ev.w, acc.w);
  }
  *(float4*)(a_out + (size_t)b * D2H_ + tid * 4) = acc;
  if (step >= 0) {
    unsigned short* hp = HA + ((size_t)step * B_ + b) * G3_ + H_ + tid * 4;
    *(ushort4*)hp = make_ushort4(f2bf(acc.x), f2bf(acc.y), f2bf(acc.z), f2bf(acc.w));
  }
}

__device__ void dec_step_body(int bid, int tid,
                              const float* __restrict__ h_in, float* __restrict__ h_out,
                              const float* __restrict__ a_in, const float* __restrict__ XE,
                              const float* __restrict__ Wih, const float* __restrict__ Whh,
                              const float* __restrict__ bhh,
                              unsigned short* __restrict__ HA, int step, float* buf) {
  const int m = tid & 31, c = tid >> 5;
  const int col = bid * 8 + c;
  const float* hrow = buf + m * 516;
  float axr = 0.f, axz = 0.f, axn = 0.f, ahr = 0.f, ahz = 0.f, ahn = 0.f;

  // phase 1: a[:, 0:512]
#pragma unroll
  for (int i = 0; i < 16; ++i) {
    int flat = (tid + i * 256) * 4;
    int mm = flat >> 9, kk = flat & 511;
    *(float4*)&buf[mm * 516 + kk] = *(const float4*)(a_in + (size_t)mm * D2H_ + kk);
  }
  __syncthreads();
  {
    const float4* wr = (const float4*)(Wih + (size_t)col * 1280 + 256);
    const float4* wz = (const float4*)(Wih + (size_t)(512 + col) * 1280 + 256);
    const float4* wn = (const float4*)(Wih + (size_t)(1024 + col) * 1280 + 256);
#pragma unroll 4
    for (int k4 = 0; k4 < 128; ++k4) {
      float4 h4 = *(const float4*)(hrow + k4 * 4);
      float4 r = wr[k4], z = wz[k4], n = wn[k4];
      axr = fmaf(h4.x, r.x, fmaf(h4.y, r.y, fmaf(h4.z, r.z, fmaf(h4.w, r.w, axr))));
      axz = fmaf(h4.x, z.x, fmaf(h4.y, z.y, fmaf(h4.z, z.z, fmaf(h4.w, z.w, axz))));
      axn = fmaf(h4.x, n.x, fmaf(h4.y, n.y, fmaf(h4.z, n.z, fmaf(h4.w, n.w, axn))));
    }
  }
  __syncthreads();

  // phase 2: a[:, 512:1024]
#pragma unroll
  for (int i = 0; i < 16; ++i) {
    int flat = (tid + i * 256) * 4;
    int mm = flat >> 9, kk = flat & 511;
    *(float4*)&buf[mm * 516 + kk] = *(const float4*)(a_in + (size_t)mm * D2H_ + 512 + kk);
  }
  __syncthreads();
  {
    const float4* wr = (const float4*)(Wih + (size_t)col * 1280 + 768);
    const float4* wz = (const float4*)(Wih + (size_t)(512 + col) * 1280 + 768);
    const float4* wn = (const float4*)(Wih + (size_t)(1024 + col) * 1280 + 768);
#pragma unroll 4
    for (int k4 = 0; k4 < 128; ++k4) {
      float4 h4 = *(const float4*)(hrow + k4 * 4);
      float4 r = wr[k4], z = wz[k4], n = wn[k4];
      axr = fmaf(h4.x, r.x, fmaf(h4.y, r.y, fmaf(h4.z, r.z, fmaf(h4.w, r.w, axr))));
      axz = fmaf(h4.x, z.x, fmaf(h4.y, z.y, fmaf(h4.z, z.z, fmaf(h4.w, z.w, axz))));
      axn = fmaf(h4.x, n.x, fmaf(h4.y, n.y, fmaf(h4.z, n.z, fmaf(h4.w, n.w, axn))));
    }
  }
  __syncthreads();

  // phase 3: h
#pragma unroll
  for (int i = 0; i < 16; ++i) {
    int flat = (tid + i * 256) * 4;
    int mm = flat >> 9, kk = flat & 511;
    *(float4*)&buf[mm * 516 + kk] = *(const float4*)(h_in + (size_t)mm * H_ + kk);
  }
  __syncthreads();
  {
    const float4* wr = (const float4*)(Whh + (size_t)col * H_);
    const float4* wz = (const float4*)(Whh + (size_t)(512 + col) * H_);
    const float4* wn = (const float4*)(Whh + (size_t)(1024 + col) * H_);
#pragma unroll 4
    for (int k4 = 0; k4 < 128; ++k4) {
      float4 h4 = *(const float4*)(hrow + k4 * 4);
      float4 r = wr[k4], z = wz[k4], n = wn[k4];
      ahr = fmaf(h4.x, r.x, fmaf(h4.y, r.y, fmaf(h4.z, r.z, fmaf(h4.w, r.w, ahr))));
      ahz = fmaf(h4.x, z.x, fmaf(h4.y, z.y, fmaf(h4.z, z.z, fmaf(h4.w, z.w, ahz))));
      ahn = fmaf(h4.x, n.x, fmaf(h4.y, n.y, fmaf(h4.z, n.z, fmaf(h4.w, n.w, ahn))));
    }
  }

  size_t xrow = ((size_t)step * B_ + m) * G3_;
  float xr = XE[xrow + col] + axr;
  float xz = XE[xrow + 512 + col] + axz;
  float xn = XE[xrow + 1024 + col] + axn;
  float r = 1.f / (1.f + expf(-(xr + ahr + bhh[col])));
  float z = 1.f / (1.f + expf(-(xz + ahz + bhh[512 + col])));
  float nn = tanhf(xn + r * (ahn + bhh[1024 + col]));
  float hold = hrow[col];
  float hnew = (1.f - z) * nn + z * hold;
  h_out[m * H_ + col] = hnew;
  HA[xrow + col] = f2bf(hnew);
}

// ---------------- persistent decoder: dec0 + a0 + 63 x (step, attend) --------
// 64 blocks. dec_step uses all 64; dec0/attend use blocks 0..31.

__global__ __launch_bounds__(256) void k_decoder(
    const int* __restrict__ inp, const float* __restrict__ enc,
    const float* __restrict__ encp,
    const float* __restrict__ dsW, const float* __restrict__ dsb,
    const float* __restrict__ XE, const float* __restrict__ dWih,
    const float* __restrict__ dWhh, const float* __restrict__ dbhh,
    const float* __restrict__ aWdec, const float* __restrict__ abdec,
    const float* __restrict__ av, const float* __restrict__ avb,
    float* __restrict__ hd0, float* __restrict__ hd1,
    float* __restrict__ adec, unsigned short* __restrict__ HAb,
    int* __restrict__ bar) {
  __shared__ float buf[32 * 516];
  __shared__ float hq[512], dp[512], vv[512], part[256], sc[128], red[128];
  __shared__ int redi[128];
  __shared__ int slen;
  const int bid = blockIdx.x, tid = threadIdx.x;
  int nsync = 0;

  // ---- dec0: lengths + last + start projection (blocks 0..31) ----
  if (bid < 32) {
    const int b = bid;
    if (tid < 128) redi[tid] = (inp[b * TI_ + tid] != 0) ? 1 : 0;
    __syncthreads();
    for (int o = 64; o > 0; o >>= 1) {
      if (tid < o) redi[tid] += redi[tid + o];
      __syncthreads();
    }
    if (tid == 0) slen = min(redi[0], TI_ - 1);
    __syncthreads();
    int len = slen;
#pragma unroll
    for (int i = 0; i < 4; ++i)
      buf[tid + i * 256] = enc[((size_t)b * TI_ + len) * D2H_ + tid + i * 256];
    __syncthreads();
#pragma unroll
    for (int jj = 0; jj < 2; ++jj) {
      int j = tid + jj * 256;
      const float4* w4 = (const float4*)(dsW + (size_t)j * D2H_);
      float acc = 0.f;
#pragma unroll 4
      for (int k4 = 0; k4 < D2H_ / 4; ++k4) {
        float4 w = w4[k4];
        float4 l4 = *(const float4*)&buf[k4 * 4];
        acc = fmaf(l4.x, w.x, fmaf(l4.y, w.y, fmaf(l4.z, w.z, fmaf(l4.w, w.w, acc))));
      }
      hd0[b * H_ + j] = acc + dsb[j];
    }
  }
  gbar(bar, 64 * (++nsync));

  // ---- a0 ----
  if (bid < 32)
    attend_body(bid, tid, hd0, enc, encp, inp, aWdec, abdec, av, avb,
                adec, HAb, -1, hq, dp, vv, part, sc, red);
  gbar(bar, 64 * (++nsync));

  // ---- 63 decoder steps ----
  for (int i = 0; i < 63; ++i) {
    const float* h_in = (i & 1) ? hd1 : hd0;
    float*       h_out = (i & 1) ? hd0 : hd1;
    dec_step_body(bid, tid, h_in, h_out, adec, XE, dWih, dWhh, dbhh, HAb, i, buf);
    gbar(bar, 64 * (++nsync));
    if (bid < 32)
      attend_body(bid, tid, h_out, enc, encp, inp, aWdec, abdec, av, avb,
                  adec, HAb, i, hq, dp, vv, part, sc, red);
    if (i < 62) gbar(bar, 64 * (++nsync));
  }
}

// ---------------- launch ------------------------------------------------------

extern "C" void kernel_launch(void* const* d_in, const int* in_sizes, int n_in,
                              void* d_out, int out_size, void* d_ws, size_t ws_size,
                              hipStream_t stream) {
  const int*   inp     = (const int*)d_in[0];
  const int*   outi    = (const int*)d_in[1];
  const float* emb_inp = (const float*)d_in[2];
  const float* emb_out = (const float*)d_in[3];
  const float* eWih_f  = (const float*)d_in[4];
  const float* eWhh_f  = (const float*)d_in[5];
  const float* ebih_f  = (const float*)d_in[6];
  const float* ebhh_f  = (const float*)d_in[7];
  const float* eWih_b  = (const float*)d_in[8];
  const float* eWhh_b  = (const float*)d_in[9];
  const float* ebih_b  = (const float*)d_in[10];
  const float* ebhh_b  = (const float*)d_in[11];
  const float* dsW     = (const float*)d_in[12];
  const float* dsb     = (const float*)d_in[13];
  const float* dWih    = (const float*)d_in[14];
  const float* dWhh    = (const float*)d_in[15];
  const float* dbih    = (const float*)d_in[16];
  const float* dbhh    = (const float*)d_in[17];
  const float* aWenc   = (const float*)d_in[18];
  const float* abenc   = (const float*)d_in[19];
  const float* aWdec   = (const float*)d_in[20];
  const float* abdec   = (const float*)d_in[21];
  const float* av      = (const float*)d_in[22];
  const float* avb     = (const float*)d_in[23];
  const float* lW      = (const float*)d_in[24];
  const float* lb      = (const float*)d_in[25];
  float* dout = (float*)d_out;

  float* ws = (float*)d_ws;
  size_t off = 0;
  auto alloc = [&](size_t n) { float* p = ws + off; off += n; return p; };
  float* x    = alloc((size_t)B_ * TI_ * E_);
  float* xp_f = alloc((size_t)B_ * TI_ * G3_);
  float* xp_b = alloc((size_t)B_ * TI_ * G3_);
  float* enc  = alloc((size_t)B_ * TI_ * D2H_);
  float* encp = alloc((size_t)B_ * TI_ * A_);
  float* xe   = alloc((size_t)63 * B_ * E_);
  float* XE   = alloc((size_t)63 * B_ * G3_);
  unsigned short* HAb = (unsigned short*)alloc((size_t)2048 * G3_ / 2);
  unsigned short* lWb = (unsigned short*)alloc((size_t)VO_ * G3_ / 2);
  float* hf0  = alloc(B_ * H_);
  float* hf1  = alloc(B_ * H_);
  float* hb0  = alloc(B_ * H_);
  float* hb1  = alloc(B_ * H_);
  float* hd0  = alloc(B_ * H_);
  float* hd1  = alloc(B_ * H_);
  float* adec = alloc(B_ * D2H_);
  int*   bar  = (int*)alloc(16);

  // init: zero h0s, HA tail rows, barrier counters
  k_init<<<192, 256, 0, stream>>>(hf0, hb0, HAb + (size_t)2016 * G3_, bar);

  // convert logits weights to bf16
  k_cvt_bf16<<<((VO_ * G3_ / 8) + 255) / 256, 256, 0, stream>>>(lW, lWb, VO_ * G3_ / 8);

  // embeddings + input projections
  k_gather_x<<<(B_ * TI_ * E_ / 4 + 255) / 256, 256, 0, stream>>>(inp, emb_inp, x);
  dim3 g1(G3_ / 128, (B_ * TI_) / 128);
  k_gemm128<<<g1, 256, 0, stream>>>(x, E_, eWih_f, E_, ebih_f, xp_f, B_ * TI_, G3_, E_);
  k_gemm128<<<g1, 256, 0, stream>>>(x, E_, eWih_b, E_, ebih_b, xp_b, B_ * TI_, G3_, E_);

  // persistent encoder (both directions, 128 steps, in-kernel grid sync)
  k_encoder<<<128, 256, 0, stream>>>(xp_f, xp_b, eWhh_f, ebhh_f, eWhh_b, ebhh_b,
                                     hf0, hf1, hb0, hb1, enc, bar);

  // enc_proj
  dim3 g2(A_ / 128, (B_ * TI_) / 128);
  k_gemm128<<<g2, 256, 0, stream>>>(enc, D2H_, aWenc, D2H_, abenc, encp, B_ * TI_, A_, D2H_);

  // decoder token embedding projection (includes dec_bih)
  k_gather_xe<<<(63 * B_ * E_ / 4 + 255) / 256, 256, 0, stream>>>(outi, emb_out, xe);
  dim3 g3(G3_ / 128, (63 * B_ + 127) / 128);
  k_gemm128<<<g3, 256, 0, stream>>>(xe, E_, dWih, E_ + D2H_, dbih, XE, 63 * B_, G3_, E_);

  // persistent decoder (dec0 + a0 + 63 steps, in-kernel grid sync)
  k_decoder<<<64, 256, 0, stream>>>(inp, enc, encp, dsW, dsb, XE, dWih, dWhh, dbhh,
                                    aWdec, abdec, av, avb, hd0, hd1, adec, HAb, bar + 1);

  // batched bf16 MFMA logits GEMM straight into d_out
  dim3 g4(VO_ / 128, 16);
  k_logits_mfma<<<g4, 256, 0, stream>>>(HAb, lWb, lb, dout);

  // first token row
  k_first<<<(B_ * VO_ + 255) / 256, 256, 0, stream>>>(dout);
}

// Round 4
// 12003.530 us; speedup vs baseline: 1.0624x; 1.0624x over previous
//
#include <hip/hip_runtime.h>
#include <math.h>
#include <stdint.h>

#define B_   32
#define TI_  128
#define TO_  64
#define E_   256
#define H_   512
#define A_   512
#define VO_  32000
#define G3_  1536   // 3H
#define D2H_ 1024   // 2H

using short8 = __attribute__((ext_vector_type(8))) short;
using f32x4  = __attribute__((ext_vector_type(4))) float;
typedef __attribute__((ext_vector_type(2))) __bf16 bf16x2_t;

__device__ __forceinline__ unsigned short f2bf(float x) {
  uint32_t u = __builtin_bit_cast(uint32_t, x);
  uint32_t r = (u + 0x7fffu + ((u >> 16) & 1u)) >> 16;
  return (unsigned short)r;
}
__device__ __forceinline__ uint32_t pack2(float lo, float hi) {
  return (uint32_t)f2bf(lo) | ((uint32_t)f2bf(hi) << 16);
}
__device__ __forceinline__ float bflo(uint32_t u) { return __builtin_bit_cast(float, u << 16); }
__device__ __forceinline__ float bfhi(uint32_t u) { return __builtin_bit_cast(float, u & 0xffff0000u); }

#if __has_builtin(__builtin_amdgcn_fdot2_f32_bf16)
__device__ __forceinline__ float dot2bf(uint32_t a, uint32_t b, float c) {
  return __builtin_amdgcn_fdot2_f32_bf16(__builtin_bit_cast(bf16x2_t, a),
                                         __builtin_bit_cast(bf16x2_t, b), c, false);
}
#else
__device__ __forceinline__ float dot2bf(uint32_t a, uint32_t b, float c) {
  return fmaf(bfhi(a), bfhi(b), fmaf(bflo(a), bflo(b), c));
}
#endif

__device__ __forceinline__ float sigf(float x) {
  return __builtin_amdgcn_rcpf(1.f + __expf(-x));
}
__device__ __forceinline__ float tanhf_(float x) {
  return fmaf(-2.f, __builtin_amdgcn_rcpf(1.f + __expf(2.f * x)), 1.f);
}

// ---------------- init: zero HAb tail rows ----------------------------------
__global__ __launch_bounds__(256) void k_init(unsigned short* __restrict__ tail) {
  int i = blockIdx.x * 256 + threadIdx.x;
  if (i < 32 * G3_) tail[i] = 0;
}

// ---------------- f32 -> bf16 (8 elems/thread) ------------------------------
__global__ __launch_bounds__(256) void k_cvt_bf16(const float* __restrict__ in,
                                                  unsigned short* __restrict__ out, int n8) {
  int i = blockIdx.x * 256 + threadIdx.x;
  if (i >= n8) return;
  float4 a = ((const float4*)in)[2 * i];
  float4 b = ((const float4*)in)[2 * i + 1];
  uint4 o = { pack2(a.x, a.y), pack2(a.z, a.w), pack2(b.x, b.y), pack2(b.z, b.w) };
  ((uint4*)out)[i] = o;
}

// ---------------- all small weight conversions in one launch ----------------
__global__ __launch_bounds__(256) void k_cvt_multi(
    const float* __restrict__ i0, unsigned short* __restrict__ o0,   // eWhh_f 98304
    const float* __restrict__ i1, unsigned short* __restrict__ o1,   // eWhh_b 98304
    const float* __restrict__ i2, unsigned short* __restrict__ o2,   // dWhh   98304
    const float* __restrict__ i3, unsigned short* __restrict__ o3,   // aWdec  32768
    const float* __restrict__ i4, unsigned short* __restrict__ o4,   // dWih  245760
    const float* __restrict__ i5, unsigned short* __restrict__ o5,   // aWenc  65536
    const float* __restrict__ i6, unsigned short* __restrict__ o6,   // eWih_f 49152
    const float* __restrict__ i7, unsigned short* __restrict__ o7) { // eWih_b 49152
  int u = blockIdx.x * 256 + threadIdx.x;
  const float* in; unsigned short* out; int lu;
  if      (u < 98304)  { in = i0; out = o0; lu = u; }
  else if (u < 196608) { in = i1; out = o1; lu = u - 98304; }
  else if (u < 294912) { in = i2; out = o2; lu = u - 196608; }
  else if (u < 327680) { in = i3; out = o3; lu = u - 294912; }
  else if (u < 573440) { in = i4; out = o4; lu = u - 327680; }
  else if (u < 638976) { in = i5; out = o5; lu = u - 573440; }
  else if (u < 688128) { in = i6; out = o6; lu = u - 638976; }
  else if (u < 737280) { in = i7; out = o7; lu = u - 688128; }
  else return;
  float4 a = ((const float4*)in)[2 * lu];
  float4 b = ((const float4*)in)[2 * lu + 1];
  uint4 o = { pack2(a.x, a.y), pack2(a.z, a.w), pack2(b.x, b.y), pack2(b.z, b.w) };
  ((uint4*)out)[lu] = o;
}

// ---------------- embedding gathers (bf16 out) ------------------------------
__global__ __launch_bounds__(256) void k_gather_xb(const int* __restrict__ inp,
                                                   const float* __restrict__ emb,
                                                   unsigned short* __restrict__ xb) {
  int idx = blockIdx.x * 256 + threadIdx.x;   // 8-elem unit
  if (idx >= 4096 * 32) return;
  int row = idx >> 5, e8 = idx & 31;
  int tok = inp[row];                          // row = b*TI + t
  const float4* s = (const float4*)(emb + (size_t)tok * E_ + e8 * 8);
  float4 a = s[0], b = s[1];
  uint4 o = { pack2(a.x, a.y), pack2(a.z, a.w), pack2(b.x, b.y), pack2(b.z, b.w) };
  ((uint4*)xb)[idx] = o;
}

__global__ __launch_bounds__(256) void k_gather_xeb(const int* __restrict__ outi,
                                                    const float* __restrict__ emb,
                                                    unsigned short* __restrict__ xeb) {
  int idx = blockIdx.x * 256 + threadIdx.x;
  if (idx >= 2016 * 32) return;
  int row = idx >> 5, e8 = idx & 31;          // row = i*32 + b
  int i = row >> 5, b = row & 31;
  int tok = outi[b * TO_ + i];
  const float4* s = (const float4*)(emb + (size_t)tok * E_ + e8 * 8);
  float4 a = s[0], bb = s[1];
  uint4 o = { pack2(a.x, a.y), pack2(a.z, a.w), pack2(bb.x, bb.y), pack2(bb.z, bb.w) };
  ((uint4*)xeb)[idx] = o;
}

__global__ __launch_bounds__(256) void k_first(float* __restrict__ dout) {
  int idx = blockIdx.x * 256 + threadIdx.x;
  if (idx >= B_ * VO_) return;
  int b = idx / VO_, v = idx % VO_;
  dout[(size_t)b * TO_ * VO_ + v] = (v == 1) ? 0.f : -20.72326583694641f;
}

// ---------------- generic bf16 MFMA GEMM (m97 structure) ---------------------
// C = A[M,lda] @ Bt[N,ldb]^T (+bias). MODE 0: f32 C[m*ldc+n]; MODE 1: bf16
// C[m*ldc+n]; MODE 3: logits scatter f32 -> dout.
template <int MODE>
__global__ __launch_bounds__(256) void k_bgemm(
    const unsigned short* __restrict__ A, int lda,
    const unsigned short* __restrict__ Bt, int ldb,
    const float* __restrict__ bias,
    void* __restrict__ Cv, int ldc, int M, int N, int K) {
  __shared__ alignas(16) unsigned short As[128 * 32];
  __shared__ alignas(16) unsigned short Bs[128 * 32];
  const int tid = threadIdx.x;
  const int wave = tid >> 6, lane = tid & 63;
  const int m0 = blockIdx.y * 128, n0 = blockIdx.x * 128;
  const int wr = wave >> 1, wc = wave & 1;

  f32x4 acc[4][4];
#pragma unroll
  for (int i = 0; i < 4; ++i)
#pragma unroll
    for (int j = 0; j < 4; ++j) acc[i][j] = (f32x4){0.f, 0.f, 0.f, 0.f};

  const int srow = tid >> 2;
  const int sbyte = (tid & 3) * 16;
  const int fr = lane & 15;
  const int fkb = (lane >> 4) * 16;

  for (int k0 = 0; k0 < K; k0 += 32) {
#pragma unroll
    for (int rd = 0; rd < 2; ++rd) {
      int row = rd * 64 + srow;
      int ra = min(m0 + row, M - 1);
      const char* ga = (const char*)(A + (size_t)ra * lda + k0) + sbyte;
      const char* gb = (const char*)(Bt + (size_t)(n0 + row) * ldb + k0) + sbyte;
      __builtin_amdgcn_global_load_lds(
          (const __attribute__((address_space(1))) uint32_t*)ga,
          (__attribute__((address_space(3))) uint32_t*)((char*)As + rd * 4096 + wave * 1024),
          16, 0, 0);
      __builtin_amdgcn_global_load_lds(
          (const __attribute__((address_space(1))) uint32_t*)gb,
          (__attribute__((address_space(3))) uint32_t*)((char*)Bs + rd * 4096 + wave * 1024),
          16, 0, 0);
    }
    __syncthreads();

    short8 af[4], bf[4];
#pragma unroll
    for (int i = 0; i < 4; ++i) {
      int ar = wr * 64 + i * 16 + fr;
      int bc = wc * 64 + i * 16 + fr;
      af[i] = *(const short8*)((const char*)As + ar * 64 + fkb);
      bf[i] = *(const short8*)((const char*)Bs + bc * 64 + fkb);
    }
#pragma unroll
    for (int i = 0; i < 4; ++i)
#pragma unroll
      for (int j = 0; j < 4; ++j)
        acc[i][j] = __builtin_amdgcn_mfma_f32_16x16x32_bf16(af[i], bf[j], acc[i][j], 0, 0, 0);
    __syncthreads();
  }

  const int crow = (lane >> 4) * 4, ccol = lane & 15;
#pragma unroll
  for (int i = 0; i < 4; ++i) {
#pragma unroll
    for (int r = 0; r < 4; ++r) {
      int m = m0 + wr * 64 + i * 16 + crow + r;
      if (m >= M) continue;
#pragma unroll
      for (int j = 0; j < 4; ++j) {
        int n = n0 + wc * 64 + j * 16 + ccol;
        float v = acc[i][j][r] + (bias ? bias[n] : 0.f);
        if (MODE == 0) {
          ((float*)Cv)[(size_t)m * ldc + n] = v;
        } else if (MODE == 1) {
          ((unsigned short*)Cv)[(size_t)m * ldc + n] = f2bf(v);
        } else {
          int bb = m & 31, st = m >> 5;
          ((float*)Cv)[((size_t)bb * TO_ + st + 1) * VO_ + n] = v;
        }
      }
    }
  }
}

// ---------------- persistent encoder: 64 independent chains -----------------
// block = (dir, b). h lives in LDS; NO cross-block communication.
__global__ __launch_bounds__(256) void k_encoder(
    const unsigned short* __restrict__ xpb_f, const unsigned short* __restrict__ xpb_b,
    const unsigned short* __restrict__ Whhb_f, const float* __restrict__ bhh_f,
    const unsigned short* __restrict__ Whhb_b, const float* __restrict__ bhh_b,
    unsigned short* __restrict__ encb) {
  __shared__ alignas(16) float h[512];
  __shared__ uint32_t hb2[256];
  __shared__ uint32_t xrow[768];
  const int bid = blockIdx.x;
  const int dir = bid >> 5, b = bid & 31;
  const unsigned short* xpb = dir ? xpb_b : xpb_f;
  const unsigned short* Whh = dir ? Whhb_b : Whhb_f;
  const float* bhh = dir ? bhh_b : bhh_f;
  const int tid = threadIdx.x;
  const int c0 = 2 * tid, c1 = c0 + 1;

  h[c0] = 0.f; h[c1] = 0.f; hb2[tid] = 0u;
  const float br0 = bhh[c0], br1 = bhh[c1];
  const float bz0 = bhh[512 + c0], bz1 = bhh[512 + c1];
  const float bn0 = bhh[1024 + c0], bn1 = bhh[1024 + c1];
  const uint4* w_r0 = (const uint4*)(Whh + (size_t)c0 * 512);
  const uint4* w_r1 = (const uint4*)(Whh + (size_t)c1 * 512);
  const uint4* w_z0 = (const uint4*)(Whh + (size_t)(512 + c0) * 512);
  const uint4* w_z1 = (const uint4*)(Whh + (size_t)(512 + c1) * 512);
  const uint4* w_n0 = (const uint4*)(Whh + (size_t)(1024 + c0) * 512);
  const uint4* w_n1 = (const uint4*)(Whh + (size_t)(1024 + c1) * 512);

  for (int t = 0; t < TI_; ++t) {
    const int tt = dir ? (TI_ - 1 - t) : t;
    const uint32_t* xr = (const uint32_t*)(xpb + (size_t)(b * 128 + tt) * G3_);
    xrow[tid] = xr[tid];
    xrow[tid + 256] = xr[tid + 256];
    xrow[tid + 512] = xr[tid + 512];
    __syncthreads();

    float ar0 = 0.f, ar1 = 0.f, az0 = 0.f, az1 = 0.f, an0 = 0.f, an1 = 0.f;
#pragma unroll 4
    for (int k = 0; k < 64; ++k) {
      uint32_t p0 = hb2[4 * k], p1 = hb2[4 * k + 1], p2 = hb2[4 * k + 2], p3 = hb2[4 * k + 3];
      uint4 u;
      u = w_r0[k]; ar0 = dot2bf(p0, u.x, ar0); ar0 = dot2bf(p1, u.y, ar0);
                   ar0 = dot2bf(p2, u.z, ar0); ar0 = dot2bf(p3, u.w, ar0);
      u = w_r1[k]; ar1 = dot2bf(p0, u.x, ar1); ar1 = dot2bf(p1, u.y, ar1);
                   ar1 = dot2bf(p2, u.z, ar1); ar1 = dot2bf(p3, u.w, ar1);
      u = w_z0[k]; az0 = dot2bf(p0, u.x, az0); az0 = dot2bf(p1, u.y, az0);
                   az0 = dot2bf(p2, u.z, az0); az0 = dot2bf(p3, u.w, az0);
      u = w_z1[k]; az1 = dot2bf(p0, u.x, az1); az1 = dot2bf(p1, u.y, az1);
                   az1 = dot2bf(p2, u.z, az1); az1 = dot2bf(p3, u.w, az1);
      u = w_n0[k]; an0 = dot2bf(p0, u.x, an0); an0 = dot2bf(p1, u.y, an0);
                   an0 = dot2bf(p2, u.z, an0); an0 = dot2bf(p3, u.w, an0);
      u = w_n1[k]; an1 = dot2bf(p0, u.x, an1); an1 = dot2bf(p1, u.y, an1);
                   an1 = dot2bf(p2, u.z, an1); an1 = dot2bf(p3, u.w, an1);
    }
    uint32_t uxr = xrow[tid], uxz = xrow[256 + tid], uxn = xrow[512 + tid];
    float r0 = sigf(bflo(uxr) + ar0 + br0);
    float r1 = sigf(bfhi(uxr) + ar1 + br1);
    float z0 = sigf(bflo(uxz) + az0 + bz0);
    float z1 = sigf(bfhi(uxz) + az1 + bz1);
    float n0 = tanhf_(bflo(uxn) + r0 * (an0 + bn0));
    float n1 = tanhf_(bfhi(uxn) + r1 * (an1 + bn1));
    float hn0 = (1.f - z0) * n0 + z0 * h[c0];
    float hn1 = (1.f - z1) * n1 + z1 * h[c1];
    ((uint32_t*)encb)[(size_t)(b * 128 + tt) * 512 + dir * 256 + tid] = pack2(hn0, hn1);
    __syncthreads();
    h[c0] = hn0; h[c1] = hn1; hb2[tid] = pack2(hn0, hn1);
    __syncthreads();
  }
}

// ---------------- persistent decoder: 32 independent chains -----------------
// block = batch row b. h/pr in LDS; encp staged in LDS (padded); no barriers.
__global__ __launch_bounds__(256) void k_decoder(
    const int* __restrict__ inp,
    const unsigned short* __restrict__ encb,
    const unsigned short* __restrict__ encpb,
    const float* __restrict__ XE,
    const unsigned short* __restrict__ encWT,
    const float* __restrict__ dsW, const float* __restrict__ dsb,
    const unsigned short* __restrict__ dWhhb, const float* __restrict__ dbhh,
    const unsigned short* __restrict__ aWdecb, const float* __restrict__ abdec,
    const float* __restrict__ abenc,
    const float* __restrict__ av, const float* __restrict__ avb,
    unsigned short* __restrict__ HAb) {
  __shared__ alignas(16) uint32_t encp_s[128 * 257];   // padded stride 257
  __shared__ alignas(16) float h[512];
  __shared__ uint32_t hb2[256];
  __shared__ float pr[128];
  __shared__ uint32_t prb2[64];
  __shared__ float dp[512];
  __shared__ float red[256];
  __shared__ float msk[128];
  __shared__ alignas(16) float vstage[1024];
  const int b = blockIdx.x, tid = threadIdx.x;
  const int c0 = 2 * tid, c1 = c0 + 1;

  // stage enc_proj (bf16) into padded LDS
  {
    const uint32_t* epg = (const uint32_t*)(encpb + (size_t)b * 128 * 512);
#pragma unroll 4
    for (int i = 0; i < 128; ++i) {
      int u = tid + i * 256;
      encp_s[(u >> 8) * 257 + (u & 255)] = epg[u];
    }
  }
  if (tid < 128) msk[tid] = (inp[b * TI_ + tid] != 0) ? 1.f : 0.f;
  __syncthreads();
  if (tid < 64) {
    float s = msk[tid] + msk[tid + 64];
#pragma unroll
    for (int off = 32; off > 0; off >>= 1) s += __shfl_xor(s, off);
    if (tid == 0) red[0] = s;
  }
  __syncthreads();
  const int len = min((int)red[0], TI_ - 1);

  // dec0: last row -> h0
  {
    const uint32_t* lrow = (const uint32_t*)(encb + (size_t)(b * 128 + len) * D2H_);
    uint32_t u0 = lrow[tid], u1 = lrow[256 + tid];
    vstage[c0] = bflo(u0); vstage[c1] = bfhi(u0);
    vstage[512 + c0] = bflo(u1); vstage[512 + c1] = bfhi(u1);
    __syncthreads();
    const float4* w0 = (const float4*)(dsW + (size_t)c0 * D2H_);
    const float4* w1 = (const float4*)(dsW + (size_t)c1 * D2H_);
    float a0 = 0.f, a1 = 0.f;
#pragma unroll 4
    for (int k = 0; k < 256; ++k) {
      float4 l = *(const float4*)&vstage[4 * k];
      float4 q0 = w0[k], q1 = w1[k];
      a0 = fmaf(l.x, q0.x, fmaf(l.y, q0.y, fmaf(l.z, q0.z, fmaf(l.w, q0.w, a0))));
      a1 = fmaf(l.x, q1.x, fmaf(l.y, q1.y, fmaf(l.z, q1.z, fmaf(l.w, q1.w, a1))));
    }
    float h0v = a0 + dsb[c0], h1v = a1 + dsb[c1];
    __syncthreads();            // all vstage reads done
    h[c0] = h0v; h[c1] = h1v; hb2[tid] = pack2(h0v, h1v);
    vstage[tid] = av[tid];      // repurpose vstage[0..511] = attn_v
    vstage[256 + tid] = av[256 + tid];
    __syncthreads();
  }

  auto attend = [&](int step) {
    // dp = h @ Wdec^T + bdec + benc  (fold enc_proj bias in here)
    {
      const uint4* w0 = (const uint4*)(aWdecb + (size_t)c0 * 512);
      const uint4* w1 = (const uint4*)(aWdecb + (size_t)c1 * 512);
      float d0 = 0.f, d1 = 0.f;
#pragma unroll 8
      for (int k = 0; k < 64; ++k) {
        uint32_t p0 = hb2[4 * k], p1 = hb2[4 * k + 1], p2 = hb2[4 * k + 2], p3 = hb2[4 * k + 3];
        uint4 u0 = w0[k];
        d0 = dot2bf(p0, u0.x, d0); d0 = dot2bf(p1, u0.y, d0);
        d0 = dot2bf(p2, u0.z, d0); d0 = dot2bf(p3, u0.w, d0);
        uint4 u1 = w1[k];
        d1 = dot2bf(p0, u1.x, d1); d1 = dot2bf(p1, u1.y, d1);
        d1 = dot2bf(p2, u1.z, d1); d1 = dot2bf(p3, u1.w, d1);
      }
      dp[c0] = d0 + abdec[c0] + abenc[c0];
      dp[c1] = d1 + abdec[c1] + abenc[c1];
    }
    __syncthreads();
    // scores: half-split over a
    {
      int t = tid & 127, half = tid >> 7;
      const uint32_t* ep = encp_s + t * 257 + half * 128;
      const float* dph = dp + half * 256;
      const float* vh = vstage + half * 256;
      float s = 0.f;
#pragma unroll 4
      for (int a2 = 0; a2 < 128; ++a2) {
        uint32_t u = ep[a2];
        s = fmaf(vh[2 * a2],     tanhf_(bflo(u) + dph[2 * a2]),     s);
        s = fmaf(vh[2 * a2 + 1], tanhf_(bfhi(u) + dph[2 * a2 + 1]), s);
      }
      red[tid] = s;
    }
    __syncthreads();
    if (tid < 128) {
      float s = red[tid] + red[tid + 128] + avb[0];
      red[tid] = (msk[tid] > 0.f) ? s : -1e30f;
    }
    __syncthreads();
    if (tid < 64) {
      float m = fmaxf(red[tid], red[tid + 64]);
#pragma unroll
      for (int off = 32; off > 0; off >>= 1) m = fmaxf(m, __shfl_xor(m, off));
      if (tid == 0) dp[0] = m;
    }
    __syncthreads();
    float mx = dp[0];
    if (tid < 128) red[tid] = __expf(red[tid] - mx);
    __syncthreads();
    if (tid < 64) {
      float s2 = red[tid] + red[tid + 64];
#pragma unroll
      for (int off = 32; off > 0; off >>= 1) s2 += __shfl_xor(s2, off);
      if (tid == 0) dp[1] = s2;
    }
    __syncthreads();
    float inv = __builtin_amdgcn_rcpf(dp[1]);
    if (tid < 128) pr[tid] = red[tid] * inv;
    __syncthreads();
    if (tid < 64) prb2[tid] = pack2(pr[2 * tid], pr[2 * tid + 1]);
    if (step >= 0) {
      // context a = pr @ enc[b]  -> HAb a-part (bf16)
      const uint32_t* eb = (const uint32_t*)(encb + (size_t)b * 128 * D2H_);
      float x0 = 0.f, x1 = 0.f, x2 = 0.f, x3 = 0.f;
#pragma unroll 4
      for (int t = 0; t < 128; ++t) {
        float p = pr[t];
        uint32_t u0 = eb[(size_t)t * 512 + tid];
        uint32_t u1 = eb[(size_t)t * 512 + 256 + tid];
        x0 = fmaf(p, bflo(u0), x0); x1 = fmaf(p, bfhi(u0), x1);
        x2 = fmaf(p, bflo(u1), x2); x3 = fmaf(p, bfhi(u1), x3);
      }
      uint32_t* hrow = (uint32_t*)(HAb + ((size_t)step * 32 + b) * G3_);
      hrow[256 + tid] = pack2(x0, x1);
      hrow[512 + tid] = pack2(x2, x3);
    }
    __syncthreads();
  };

  auto gru = [&](int i) {
    float xa[6], ha[6];
#pragma unroll
    for (int g = 0; g < 3; ++g) {
      const uint4* e0 = (const uint4*)(encWT + (size_t)(g * 512 + c0) * 4096 + b * 128);
      const uint4* e1 = (const uint4*)(encWT + (size_t)(g * 512 + c1) * 4096 + b * 128);
      float s0 = 0.f, s1 = 0.f;
#pragma unroll
      for (int k = 0; k < 16; ++k) {
        uint32_t p0 = prb2[4 * k], p1 = prb2[4 * k + 1], p2 = prb2[4 * k + 2], p3 = prb2[4 * k + 3];
        uint4 u0 = e0[k];
        s0 = dot2bf(p0, u0.x, s0); s0 = dot2bf(p1, u0.y, s0);
        s0 = dot2bf(p2, u0.z, s0); s0 = dot2bf(p3, u0.w, s0);
        uint4 u1 = e1[k];
        s1 = dot2bf(p0, u1.x, s1); s1 = dot2bf(p1, u1.y, s1);
        s1 = dot2bf(p2, u1.z, s1); s1 = dot2bf(p3, u1.w, s1);
      }
      xa[g * 2] = s0; xa[g * 2 + 1] = s1;
    }
#pragma unroll
    for (int g = 0; g < 3; ++g) {
      const uint4* w0 = (const uint4*)(dWhhb + (size_t)(g * 512 + c0) * 512);
      const uint4* w1 = (const uint4*)(dWhhb + (size_t)(g * 512 + c1) * 512);
      float s0 = 0.f, s1 = 0.f;
#pragma unroll 8
      for (int k = 0; k < 64; ++k) {
        uint32_t p0 = hb2[4 * k], p1 = hb2[4 * k + 1], p2 = hb2[4 * k + 2], p3 = hb2[4 * k + 3];
        uint4 u0 = w0[k];
        s0 = dot2bf(p0, u0.x, s0); s0 = dot2bf(p1, u0.y, s0);
        s0 = dot2bf(p2, u0.z, s0); s0 = dot2bf(p3, u0.w, s0);
        uint4 u1 = w1[k];
        s1 = dot2bf(p0, u1.x, s1); s1 = dot2bf(p1, u1.y, s1);
        s1 = dot2bf(p2, u1.z, s1); s1 = dot2bf(p3, u1.w, s1);
      }
      ha[g * 2] = s0; ha[g * 2 + 1] = s1;
    }
    const float* xrow = XE + ((size_t)i * 32 + b) * G3_;
    float r0 = sigf(xrow[c0] + xa[0] + ha[0] + dbhh[c0]);
    float r1 = sigf(xrow[c1] + xa[1] + ha[1] + dbhh[c1]);
    float z0 = sigf(xrow[512 + c0] + xa[2] + ha[2] + dbhh[512 + c0]);
    float z1 = sigf(xrow[512 + c1] + xa[3] + ha[3] + dbhh[512 + c1]);
    float n0 = tanhf_(xrow[1024 + c0] + xa[4] + r0 * (ha[4] + dbhh[1024 + c0]));
    float n1 = tanhf_(xrow[1024 + c1] + xa[5] + r1 * (ha[5] + dbhh[1024 + c1]));
    float hn0 = (1.f - z0) * n0 + z0 * h[c0];
    float hn1 = (1.f - z1) * n1 + z1 * h[c1];
    ((uint32_t*)(HAb + ((size_t)i * 32 + b) * G3_))[tid] = pack2(hn0, hn1);
    __syncthreads();
    h[c0] = hn0; h[c1] = hn1; hb2[tid] = pack2(hn0, hn1);
    __syncthreads();
  };

  attend(-1);
  for (int i = 0; i < 63; ++i) {
    gru(i);
    attend(i);
  }
}

// ---------------- launch ------------------------------------------------------

extern "C" void kernel_launch(void* const* d_in, const int* in_sizes, int n_in,
                              void* d_out, int out_size, void* d_ws, size_t ws_size,
                              hipStream_t stream) {
  const int*   inp     = (const int*)d_in[0];
  const int*   outi    = (const int*)d_in[1];
  const float* emb_inp = (const float*)d_in[2];
  const float* emb_out = (const float*)d_in[3];
  const float* eWih_f  = (const float*)d_in[4];
  const float* eWhh_f  = (const float*)d_in[5];
  const float* ebih_f  = (const float*)d_in[6];
  const float* ebhh_f  = (const float*)d_in[7];
  const float* eWih_b  = (const float*)d_in[8];
  const float* eWhh_b  = (const float*)d_in[9];
  const float* ebih_b  = (const float*)d_in[10];
  const float* ebhh_b  = (const float*)d_in[11];
  const float* dsW     = (const float*)d_in[12];
  const float* dsb     = (const float*)d_in[13];
  const float* dWih    = (const float*)d_in[14];
  const float* dWhh    = (const float*)d_in[15];
  const float* dbih    = (const float*)d_in[16];
  const float* dbhh    = (const float*)d_in[17];
  const float* aWenc   = (const float*)d_in[18];
  const float* abenc   = (const float*)d_in[19];
  const float* aWdec   = (const float*)d_in[20];
  const float* abdec   = (const float*)d_in[21];
  const float* av      = (const float*)d_in[22];
  const float* avb     = (const float*)d_in[23];
  const float* lW      = (const float*)d_in[24];
  const float* lb      = (const float*)d_in[25];
  float* dout = (float*)d_out;

  char* ws = (char*)d_ws;
  size_t off = 0;
  auto alloc = [&](size_t bytes) {
    void* p = ws + off;
    off += (bytes + 255) & ~(size_t)255;
    return p;
  };
  unsigned short* xb      = (unsigned short*)alloc((size_t)4096 * 256 * 2);
  unsigned short* xeb     = (unsigned short*)alloc((size_t)2016 * 256 * 2);
  unsigned short* xpb_f   = (unsigned short*)alloc((size_t)4096 * G3_ * 2);
  unsigned short* xpb_b   = (unsigned short*)alloc((size_t)4096 * G3_ * 2);
  unsigned short* encb    = (unsigned short*)alloc((size_t)4096 * D2H_ * 2);
  unsigned short* encpb   = (unsigned short*)alloc((size_t)4096 * 512 * 2);
  unsigned short* encWT   = (unsigned short*)alloc((size_t)G3_ * 4096 * 2);
  float*          XE      = (float*)alloc((size_t)2016 * G3_ * 4);
  unsigned short* HAb     = (unsigned short*)alloc((size_t)2048 * G3_ * 2);
  unsigned short* lWb     = (unsigned short*)alloc((size_t)VO_ * G3_ * 2);
  unsigned short* eWhhb_f = (unsigned short*)alloc((size_t)G3_ * 512 * 2);
  unsigned short* eWhhb_b = (unsigned short*)alloc((size_t)G3_ * 512 * 2);
  unsigned short* dWhhb   = (unsigned short*)alloc((size_t)G3_ * 512 * 2);
  unsigned short* aWdecb  = (unsigned short*)alloc((size_t)512 * 512 * 2);
  unsigned short* dWihb   = (unsigned short*)alloc((size_t)G3_ * 1280 * 2);
  unsigned short* aWencb  = (unsigned short*)alloc((size_t)512 * D2H_ * 2);
  unsigned short* eWihb_f = (unsigned short*)alloc((size_t)G3_ * 256 * 2);
  unsigned short* eWihb_b = (unsigned short*)alloc((size_t)G3_ * 256 * 2);

  // init + weight conversions
  k_init<<<192, 256, 0, stream>>>(HAb + (size_t)2016 * G3_);
  k_cvt_multi<<<2880, 256, 0, stream>>>(eWhh_f, eWhhb_f, eWhh_b, eWhhb_b,
                                        dWhh, dWhhb, aWdec, aWdecb,
                                        dWih, dWihb, aWenc, aWencb,
                                        eWih_f, eWihb_f, eWih_b, eWihb_b);
  k_cvt_bf16<<<24000, 256, 0, stream>>>(lW, lWb, VO_ * G3_ / 8);

  // embeddings
  k_gather_xb<<<512, 256, 0, stream>>>(inp, emb_inp, xb);
  k_gather_xeb<<<252, 256, 0, stream>>>(outi, emb_out, xeb);

  // xp = x @ eWih^T + ebih   (bf16 out)
  {
    dim3 g(12, 32);
    k_bgemm<1><<<g, 256, 0, stream>>>(xb, 256, eWihb_f, 256, ebih_f, xpb_f, G3_, 4096, G3_, 256);
    k_bgemm<1><<<g, 256, 0, stream>>>(xb, 256, eWihb_b, 256, ebih_b, xpb_b, G3_, 4096, G3_, 256);
  }

  // encoder (64 independent chains, no barriers)
  k_encoder<<<64, 256, 0, stream>>>(xpb_f, xpb_b, eWhhb_f, ebhh_f, eWhhb_b, ebhh_b, encb);

  // enc_proj (bf16 out, bias folded into decoder dp)
  {
    dim3 g(4, 32);
    k_bgemm<1><<<g, 256, 0, stream>>>(encb, D2H_, aWencb, D2H_, nullptr, encpb, 512, 4096, 512, D2H_);
  }
  // encW^T = dWih_a @ enc^T  (bf16 out [1536][4096])
  {
    dim3 g(32, 12);
    k_bgemm<1><<<g, 256, 0, stream>>>(dWihb + 256, 1280, encb, D2H_, nullptr, encWT, 4096, G3_, 4096, D2H_);
  }
  // XE = xe @ dWih_e^T + dbih (f32 out)
  {
    dim3 g(12, 16);
    k_bgemm<0><<<g, 256, 0, stream>>>(xeb, 256, dWihb, 1280, dbih, XE, G3_, 2016, G3_, 256);
  }

  // decoder (32 independent chains, no barriers)
  k_decoder<<<32, 256, 0, stream>>>(inp, encb, encpb, XE, encWT, dsW, dsb,
                                    dWhhb, dbhh, aWdecb, abdec, abenc, av, avb, HAb);

  // logits
  {
    dim3 g(250, 16);
    k_bgemm<3><<<g, 256, 0, stream>>>(HAb, G3_, lWb, G3_, lb, dout, 0, 2016, VO_, G3_);
  }
  k_first<<<4000, 256, 0, stream>>>(dout);
}

// Round 5
// 11100.938 us; speedup vs baseline: 1.1487x; 1.0813x over previous
//
#include <hip/hip_runtime.h>
#include <math.h>
#include <stdint.h>

#define B_   32
#define TI_  128
#define TO_  64
#define E_   256
#define H_   512
#define A_   512
#define VO_  32000
#define G3_  1536   // 3H
#define D2H_ 1024   // 2H

using short8 = __attribute__((ext_vector_type(8))) short;
using f32x4  = __attribute__((ext_vector_type(4))) float;
typedef __attribute__((ext_vector_type(2))) __bf16 bf16x2_t;

__device__ __forceinline__ unsigned short f2bf(float x) {
  uint32_t u = __builtin_bit_cast(uint32_t, x);
  uint32_t r = (u + 0x7fffu + ((u >> 16) & 1u)) >> 16;
  return (unsigned short)r;
}
__device__ __forceinline__ uint32_t pack2(float lo, float hi) {
  return (uint32_t)f2bf(lo) | ((uint32_t)f2bf(hi) << 16);
}
__device__ __forceinline__ float bflo(uint32_t u) { return __builtin_bit_cast(float, u << 16); }
__device__ __forceinline__ float bfhi(uint32_t u) { return __builtin_bit_cast(float, u & 0xffff0000u); }

#if __has_builtin(__builtin_amdgcn_fdot2_f32_bf16)
__device__ __forceinline__ float dot2bf(uint32_t a, uint32_t b, float c) {
  return __builtin_amdgcn_fdot2_f32_bf16(__builtin_bit_cast(bf16x2_t, a),
                                         __builtin_bit_cast(bf16x2_t, b), c, false);
}
#else
__device__ __forceinline__ float dot2bf(uint32_t a, uint32_t b, float c) {
  return fmaf(bfhi(a), bfhi(b), fmaf(bflo(a), bflo(b), c));
}
#endif

__device__ __forceinline__ float sigf(float x) {
  return __builtin_amdgcn_rcpf(1.f + __expf(-x));
}
__device__ __forceinline__ float tanhf_(float x) {
  return fmaf(-2.f, __builtin_amdgcn_rcpf(1.f + __expf(2.f * x)), 1.f);
}

// ---------------- init: zero HAb tail rows ----------------------------------
__global__ __launch_bounds__(256) void k_init(unsigned short* __restrict__ tail) {
  int i = blockIdx.x * 256 + threadIdx.x;
  if (i < 32 * G3_) tail[i] = 0;
}

// ---------------- f32 -> bf16 row-major (8 elems/thread) --------------------
__global__ __launch_bounds__(256) void k_cvt_bf16(const float* __restrict__ in,
                                                  unsigned short* __restrict__ out, int n8) {
  int i = blockIdx.x * 256 + threadIdx.x;
  if (i >= n8) return;
  float4 a = ((const float4*)in)[2 * i];
  float4 b = ((const float4*)in)[2 * i + 1];
  uint4 o = { pack2(a.x, a.y), pack2(a.z, a.w), pack2(b.x, b.y), pack2(b.z, b.w) };
  ((uint4*)out)[i] = o;
}

// row-major bf16 conversions still needed for MFMA GEMM operands
__global__ __launch_bounds__(256) void k_cvt_multi(
    const float* __restrict__ i0, unsigned short* __restrict__ o0,   // dWih  245760 u8
    const float* __restrict__ i1, unsigned short* __restrict__ o1,   // aWenc  65536
    const float* __restrict__ i2, unsigned short* __restrict__ o2,   // eWih_f 49152
    const float* __restrict__ i3, unsigned short* __restrict__ o3) { // eWih_b 49152
  int u = blockIdx.x * 256 + threadIdx.x;
  const float* in; unsigned short* out; int lu;
  if      (u < 245760) { in = i0; out = o0; lu = u; }
  else if (u < 311296) { in = i1; out = o1; lu = u - 245760; }
  else if (u < 360448) { in = i2; out = o2; lu = u - 311296; }
  else if (u < 409600) { in = i3; out = o3; lu = u - 360448; }
  else return;
  float4 a = ((const float4*)in)[2 * lu];
  float4 b = ((const float4*)in)[2 * lu + 1];
  uint4 o = { pack2(a.x, a.y), pack2(a.z, a.w), pack2(b.x, b.y), pack2(b.z, b.w) };
  ((uint4*)out)[lu] = o;
}

// transposed-pack: in f32 [N][K] -> out uint32 [K/2][N], out[kp*N+c]=pack(in[c][2kp],in[c][2kp+1])
__global__ __launch_bounds__(256) void k_cvt_tp(
    const float* __restrict__ i0, uint32_t* __restrict__ o0,   // eWhh_f N=1536 K=512 -> 393216
    const float* __restrict__ i1, uint32_t* __restrict__ o1,   // eWhh_b 393216
    const float* __restrict__ i2, uint32_t* __restrict__ o2,   // dWhh   393216
    const float* __restrict__ i3, uint32_t* __restrict__ o3) { // aWdec N=512 K=512 -> 131072
  int u = blockIdx.x * 256 + threadIdx.x;
  const float* in; uint32_t* out; int lu, N;
  if      (u < 393216)  { in = i0; out = o0; lu = u;          N = 1536; }
  else if (u < 786432)  { in = i1; out = o1; lu = u - 393216; N = 1536; }
  else if (u < 1179648) { in = i2; out = o2; lu = u - 786432; N = 1536; }
  else if (u < 1310720) { in = i3; out = o3; lu = u - 1179648; N = 512; }
  else return;
  int c = lu % N, kp = lu / N;
  const float* p = in + (size_t)c * 512 + 2 * kp;
  out[lu] = pack2(p[0], p[1]);
}

// repack encWA [4096][1536] bf16 -> EWPd [(b*64+tp)*1536+g] uint32 (t-pairs)
__global__ __launch_bounds__(256) void k_packT(const unsigned short* __restrict__ encWA,
                                               uint32_t* __restrict__ EWPd) {
  int idx = blockIdx.x * 256 + threadIdx.x;
  if (idx >= 32 * 64 * 1536) return;
  int g = idx % 1536, q = idx / 1536;
  int b = q >> 6, tp = q & 63;
  size_t r0 = ((size_t)(b * 128 + 2 * tp)) * 1536 + g;
  EWPd[idx] = (uint32_t)encWA[r0] | ((uint32_t)encWA[r0 + 1536] << 16);
}

// ---------------- embedding gathers (bf16 out) ------------------------------
__global__ __launch_bounds__(256) void k_gather_xb(const int* __restrict__ inp,
                                                   const float* __restrict__ emb,
                                                   unsigned short* __restrict__ xb) {
  int idx = blockIdx.x * 256 + threadIdx.x;
  if (idx >= 4096 * 32) return;
  int row = idx >> 5, e8 = idx & 31;
  int tok = inp[row];
  const float4* s = (const float4*)(emb + (size_t)tok * E_ + e8 * 8);
  float4 a = s[0], b = s[1];
  uint4 o = { pack2(a.x, a.y), pack2(a.z, a.w), pack2(b.x, b.y), pack2(b.z, b.w) };
  ((uint4*)xb)[idx] = o;
}

__global__ __launch_bounds__(256) void k_gather_xeb(const int* __restrict__ outi,
                                                    const float* __restrict__ emb,
                                                    unsigned short* __restrict__ xeb) {
  int idx = blockIdx.x * 256 + threadIdx.x;
  if (idx >= 2016 * 32) return;
  int row = idx >> 5, e8 = idx & 31;
  int i = row >> 5, b = row & 31;
  int tok = outi[b * TO_ + i];
  const float4* s = (const float4*)(emb + (size_t)tok * E_ + e8 * 8);
  float4 a = s[0], bb = s[1];
  uint4 o = { pack2(a.x, a.y), pack2(a.z, a.w), pack2(bb.x, bb.y), pack2(bb.z, bb.w) };
  ((uint4*)xeb)[idx] = o;
}

__global__ __launch_bounds__(256) void k_first(float* __restrict__ dout) {
  int idx = blockIdx.x * 256 + threadIdx.x;
  if (idx >= B_ * VO_) return;
  int b = idx / VO_, v = idx % VO_;
  dout[(size_t)b * TO_ * VO_ + v] = (v == 1) ? 0.f : -20.72326583694641f;
}

// ---------------- generic bf16 MFMA GEMM (m97 structure) ---------------------
template <int MODE>
__global__ __launch_bounds__(256) void k_bgemm(
    const unsigned short* __restrict__ A, int lda,
    const unsigned short* __restrict__ Bt, int ldb,
    const float* __restrict__ bias,
    void* __restrict__ Cv, int ldc, int M, int N, int K) {
  __shared__ alignas(16) unsigned short As[128 * 32];
  __shared__ alignas(16) unsigned short Bs[128 * 32];
  const int tid = threadIdx.x;
  const int wave = tid >> 6, lane = tid & 63;
  const int m0 = blockIdx.y * 128, n0 = blockIdx.x * 128;
  const int wr = wave >> 1, wc = wave & 1;

  f32x4 acc[4][4];
#pragma unroll
  for (int i = 0; i < 4; ++i)
#pragma unroll
    for (int j = 0; j < 4; ++j) acc[i][j] = (f32x4){0.f, 0.f, 0.f, 0.f};

  const int srow = tid >> 2;
  const int sbyte = (tid & 3) * 16;
  const int fr = lane & 15;
  const int fkb = (lane >> 4) * 16;

  for (int k0 = 0; k0 < K; k0 += 32) {
#pragma unroll
    for (int rd = 0; rd < 2; ++rd) {
      int row = rd * 64 + srow;
      int ra = min(m0 + row, M - 1);
      const char* ga = (const char*)(A + (size_t)ra * lda + k0) + sbyte;
      const char* gb = (const char*)(Bt + (size_t)(n0 + row) * ldb + k0) + sbyte;
      __builtin_amdgcn_global_load_lds(
          (const __attribute__((address_space(1))) uint32_t*)ga,
          (__attribute__((address_space(3))) uint32_t*)((char*)As + rd * 4096 + wave * 1024),
          16, 0, 0);
      __builtin_amdgcn_global_load_lds(
          (const __attribute__((address_space(1))) uint32_t*)gb,
          (__attribute__((address_space(3))) uint32_t*)((char*)Bs + rd * 4096 + wave * 1024),
          16, 0, 0);
    }
    __syncthreads();

    short8 af[4], bf[4];
#pragma unroll
    for (int i = 0; i < 4; ++i) {
      int ar = wr * 64 + i * 16 + fr;
      int bc = wc * 64 + i * 16 + fr;
      af[i] = *(const short8*)((const char*)As + ar * 64 + fkb);
      bf[i] = *(const short8*)((const char*)Bs + bc * 64 + fkb);
    }
#pragma unroll
    for (int i = 0; i < 4; ++i)
#pragma unroll
      for (int j = 0; j < 4; ++j)
        acc[i][j] = __builtin_amdgcn_mfma_f32_16x16x32_bf16(af[i], bf[j], acc[i][j], 0, 0, 0);
    __syncthreads();
  }

  const int crow = (lane >> 4) * 4, ccol = lane & 15;
#pragma unroll
  for (int i = 0; i < 4; ++i) {
#pragma unroll
    for (int r = 0; r < 4; ++r) {
      int m = m0 + wr * 64 + i * 16 + crow + r;
      if (m >= M) continue;
#pragma unroll
      for (int j = 0; j < 4; ++j) {
        int n = n0 + wc * 64 + j * 16 + ccol;
        float v = acc[i][j][r] + (bias ? bias[n] : 0.f);
        if (MODE == 0) {
          ((float*)Cv)[(size_t)m * ldc + n] = v;
        } else if (MODE == 1) {
          ((unsigned short*)Cv)[(size_t)m * ldc + n] = f2bf(v);
        } else {
          int bb = m & 31, st = m >> 5;
          ((float*)Cv)[((size_t)bb * TO_ + st + 1) * VO_ + n] = v;
        }
      }
    }
  }
}

// ---------------- persistent encoder: 64 chains, 1024 thr, coalesced W ------
// block = (dir,b). EWP layout [kp in 256][1536 gcols] uint32.
__global__ __launch_bounds__(1024, 4) void k_encoder(
    const unsigned short* __restrict__ xpb_f, const unsigned short* __restrict__ xpb_b,
    const uint32_t* __restrict__ EWPf, const float* __restrict__ bhh_f,
    const uint32_t* __restrict__ EWPb, const float* __restrict__ bhh_b,
    unsigned short* __restrict__ encb) {
  __shared__ uint32_t xrow[768];
  __shared__ float hf[512];
  __shared__ uint32_t hb2[256];
  const int bid = blockIdx.x;
  const int dir = bid >> 5, b = bid & 31;
  const unsigned short* xpb = dir ? xpb_b : xpb_f;
  const uint32_t* EWP = dir ? EWPb : EWPf;
  const float* bhh = dir ? bhh_b : bhh_f;
  const int tid = threadIdx.x;
  const int col = tid >> 1, kh = tid & 1;

  if (tid < 512) hf[tid] = 0.f;
  if (tid < 256) hb2[tid] = 0u;
  float br = 0.f, bz = 0.f, bn = 0.f;
  if (kh == 0) { br = bhh[col]; bz = bhh[512 + col]; bn = bhh[1024 + col]; }
  uint32_t* encw = (uint32_t*)encb;

  for (int t = 0; t < TI_; ++t) {
    const int tt = dir ? (TI_ - 1 - t) : t;
    const uint32_t* xr = (const uint32_t*)(xpb + (size_t)(b * 128 + tt) * G3_);
    if (tid < 768) xrow[tid] = xr[tid];
    __syncthreads();

    float ar = 0.f, az = 0.f, an = 0.f;
    const uint32_t* wp = EWP + (size_t)(kh * 128) * 1536 + col;
#pragma unroll 8
    for (int k = 0; k < 128; ++k) {
      uint32_t hv = hb2[kh * 128 + k];
      ar = dot2bf(hv, wp[0], ar);
      az = dot2bf(hv, wp[512], az);
      an = dot2bf(hv, wp[1024], an);
      wp += 1536;
    }
    ar += __shfl_xor(ar, 1);
    az += __shfl_xor(az, 1);
    an += __shfl_xor(an, 1);

    float hnew = 0.f;
    if (kh == 0) {
      uint32_t ur = xrow[col >> 1], uz = xrow[256 + (col >> 1)], un = xrow[512 + (col >> 1)];
      float xrv = (col & 1) ? bfhi(ur) : bflo(ur);
      float xzv = (col & 1) ? bfhi(uz) : bflo(uz);
      float xnv = (col & 1) ? bfhi(un) : bflo(un);
      float r = sigf(xrv + ar + br);
      float z = sigf(xzv + az + bz);
      float n = tanhf_(xnv + r * (an + bn));
      hnew = (1.f - z) * n + z * hf[col];
    }
    __syncthreads();                       // hb2/hf reads done
    float hnb = __shfl_down(hnew, 2);
    if ((tid & 3) == 0)
      encw[(size_t)(b * 128 + tt) * 512 + dir * 256 + (tid >> 2)] = pack2(hnew, hnb);
    if (kh == 0) hf[col] = hnew;
    __syncthreads();
    if (tid < 256) hb2[tid] = pack2(hf[2 * tid], hf[2 * tid + 1]);
    __syncthreads();
  }
}

// ---------------- persistent decoder: 32 chains, 1024 thr -------------------
__global__ __launch_bounds__(1024, 4) void k_decoder(
    const int* __restrict__ inp,
    const unsigned short* __restrict__ encb,
    const unsigned short* __restrict__ encpb,
    const float* __restrict__ XE,
    const uint32_t* __restrict__ EWPd,    // [(b*64+tp)*1536+g]
    const uint32_t* __restrict__ WHPd,    // [kp*1536+g]
    const uint32_t* __restrict__ WDPd,    // [kp*512+c]
    const float* __restrict__ dsW, const float* __restrict__ dsb,
    const float* __restrict__ dbhh,
    const float* __restrict__ abdec, const float* __restrict__ abenc,
    const float* __restrict__ av, const float* __restrict__ avb,
    unsigned short* __restrict__ HAb) {
  __shared__ float hf[512];
  __shared__ uint32_t hb2[256];
  __shared__ uint32_t prb2[64];
  __shared__ float pr[128];
  __shared__ float sc[128];
  __shared__ float msk[128];
  __shared__ float dp[512];
  __shared__ float vavf[512];
  __shared__ float red[1024];
  __shared__ float red2[1024];
  __shared__ float dpx[4];
  const int b = blockIdx.x, tid = threadIdx.x;
  const int col = tid >> 1, kh = tid & 1;

  float db_r = 0.f, db_z = 0.f, db_n = 0.f, adb = 0.f;
  if (kh == 0) {
    db_r = dbhh[col]; db_z = dbhh[512 + col]; db_n = dbhh[1024 + col];
    adb = abdec[col] + abenc[col];
  }
  const float avb0 = avb[0];

  if (tid < 128) msk[tid] = (inp[b * TI_ + tid] != 0) ? 1.f : 0.f;
  if (tid < 512) vavf[tid] = av[tid];
  __syncthreads();
  if (tid < 64) {
    float s = msk[tid] + msk[tid + 64];
#pragma unroll
    for (int o = 32; o > 0; o >>= 1) s += __shfl_xor(s, o);
    if (tid == 0) dpx[0] = s;
  }
  __syncthreads();
  const int len = min((int)dpx[0], TI_ - 1);

  // ---- dec0: h0 = enc[b,len] @ dsW^T + dsb ----
  if (tid < 512) {
    uint32_t u = ((const uint32_t*)encb)[(size_t)(b * 128 + len) * 512 + tid];
    red[2 * tid] = bflo(u);
    red[2 * tid + 1] = bfhi(u);
  }
  __syncthreads();
  {
    const float4* w = (const float4*)(dsW + (size_t)col * D2H_ + kh * 512);
    float acc = 0.f;
#pragma unroll 8
    for (int k = 0; k < 128; ++k) {
      float4 l = ((const float4*)red)[kh * 128 + k];
      float4 q = w[k];
      acc = fmaf(l.x, q.x, fmaf(l.y, q.y, fmaf(l.z, q.z, fmaf(l.w, q.w, acc))));
    }
    acc += __shfl_xor(acc, 1);
    __syncthreads();
    if (kh == 0) hf[col] = acc + dsb[col];
    __syncthreads();
    if (tid < 256) hb2[tid] = pack2(hf[2 * tid], hf[2 * tid + 1]);
    __syncthreads();
  }

  auto attend = [&](int step) {
    // dp = h @ Wdec^T + bdec + benc
    {
      const uint32_t* wp = WDPd + (size_t)(kh * 128) * 512 + col;
      float d_ = 0.f;
#pragma unroll 8
      for (int k = 0; k < 128; ++k) {
        d_ = dot2bf(hb2[kh * 128 + k], wp[0], d_);
        wp += 512;
      }
      d_ += __shfl_xor(d_, 1);
      if (kh == 0) dp[col] = d_ + adb;
    }
    __syncthreads();
    // scores: 8 threads per t
    {
      int t = tid >> 3, s8 = tid & 7;
      const uint32_t* ep = (const uint32_t*)encpb + (size_t)(b * 128 + t) * 256 + s8;
      float s = 0.f;
#pragma unroll 4
      for (int i = 0; i < 32; ++i) {
        int j = s8 + 8 * i;
        uint32_t u = ep[8 * i];
        float2 d2 = *(const float2*)&dp[2 * j];
        float2 v2 = *(const float2*)&vavf[2 * j];
        s = fmaf(v2.x, tanhf_(bflo(u) + d2.x), s);
        s = fmaf(v2.y, tanhf_(bfhi(u) + d2.y), s);
      }
      s += __shfl_xor(s, 1);
      s += __shfl_xor(s, 2);
      s += __shfl_xor(s, 4);
      if (s8 == 0) sc[t] = s;
    }
    __syncthreads();
    if (tid < 128) sc[tid] = (msk[tid] > 0.f) ? sc[tid] + avb0 : -1e30f;
    __syncthreads();
    if (tid < 64) {
      float m = fmaxf(sc[tid], sc[tid + 64]);
#pragma unroll
      for (int o = 32; o > 0; o >>= 1) m = fmaxf(m, __shfl_xor(m, o));
      if (tid == 0) dpx[1] = m;
    }
    __syncthreads();
    if (tid < 128) pr[tid] = __expf(sc[tid] - dpx[1]);
    __syncthreads();
    if (tid < 64) {
      float s2 = pr[tid] + pr[tid + 64];
#pragma unroll
      for (int o = 32; o > 0; o >>= 1) s2 += __shfl_xor(s2, o);
      if (tid == 0) dpx[2] = s2;
    }
    __syncthreads();
    float inv = __builtin_amdgcn_rcpf(dpx[2]);
    if (tid < 128) pr[tid] *= inv;
    __syncthreads();
    if (tid < 64) prb2[tid] = pack2(pr[2 * tid], pr[2 * tid + 1]);
    if (step >= 0) {
      // context = pr @ enc[b] -> HAb a-part
      const uint32_t* eb = (const uint32_t*)encb + (size_t)b * 128 * 512;
      int d = tid & 511, tq = tid >> 9;
      float x0 = 0.f, x1 = 0.f;
#pragma unroll 4
      for (int k = 0; k < 64; ++k) {
        int t = tq * 64 + k;
        float p = pr[t];
        uint32_t u = eb[(size_t)t * 512 + d];
        x0 = fmaf(p, bflo(u), x0);
        x1 = fmaf(p, bfhi(u), x1);
      }
      red[tid] = x0; red2[tid] = x1;
      __syncthreads();
      if (tid < 512) {
        x0 = red[tid] + red[tid + 512];
        x1 = red2[tid] + red2[tid + 512];
        uint32_t* hrow = (uint32_t*)(HAb + ((size_t)step * 32 + b) * G3_);
        hrow[256 + tid] = pack2(x0, x1);
      }
    }
    __syncthreads();
  };

  auto gru = [&](int i) {
    float xr_ = 0.f, xz_ = 0.f, xn_ = 0.f, hr_ = 0.f, hz_ = 0.f, hn_ = 0.f;
    {
      const uint32_t* ew = EWPd + ((size_t)b * 64 + kh * 32) * 1536 + col;
#pragma unroll 8
      for (int k = 0; k < 32; ++k) {
        uint32_t pv = prb2[kh * 32 + k];
        xr_ = dot2bf(pv, ew[0], xr_);
        xz_ = dot2bf(pv, ew[512], xz_);
        xn_ = dot2bf(pv, ew[1024], xn_);
        ew += 1536;
      }
    }
    {
      const uint32_t* wp = WHPd + (size_t)(kh * 128) * 1536 + col;
#pragma unroll 8
      for (int k = 0; k < 128; ++k) {
        uint32_t hv = hb2[kh * 128 + k];
        hr_ = dot2bf(hv, wp[0], hr_);
        hz_ = dot2bf(hv, wp[512], hz_);
        hn_ = dot2bf(hv, wp[1024], hn_);
        wp += 1536;
      }
    }
    float t_r = xr_ + hr_; t_r += __shfl_xor(t_r, 1);
    float t_z = xz_ + hz_; t_z += __shfl_xor(t_z, 1);
    xn_ += __shfl_xor(xn_, 1);
    hn_ += __shfl_xor(hn_, 1);

    float hnew = 0.f;
    if (kh == 0) {
      const float* xrow = XE + ((size_t)i * 32 + b) * G3_;
      float r = sigf(xrow[col] + t_r + db_r);
      float z = sigf(xrow[512 + col] + t_z + db_z);
      float n = tanhf_(xrow[1024 + col] + xn_ + r * (hn_ + db_n));
      hnew = (1.f - z) * n + z * hf[col];
    }
    __syncthreads();
    float hnb = __shfl_down(hnew, 2);
    if ((tid & 3) == 0)
      ((uint32_t*)(HAb + ((size_t)i * 32 + b) * G3_))[tid >> 2] = pack2(hnew, hnb);
    if (kh == 0) hf[col] = hnew;
    __syncthreads();
    if (tid < 256) hb2[tid] = pack2(hf[2 * tid], hf[2 * tid + 1]);
    __syncthreads();
  };

  attend(-1);
  for (int i = 0; i < 63; ++i) {
    gru(i);
    attend(i);
  }
}

// ---------------- launch ------------------------------------------------------

extern "C" void kernel_launch(void* const* d_in, const int* in_sizes, int n_in,
                              void* d_out, int out_size, void* d_ws, size_t ws_size,
                              hipStream_t stream) {
  const int*   inp     = (const int*)d_in[0];
  const int*   outi    = (const int*)d_in[1];
  const float* emb_inp = (const float*)d_in[2];
  const float* emb_out = (const float*)d_in[3];
  const float* eWih_f  = (const float*)d_in[4];
  const float* eWhh_f  = (const float*)d_in[5];
  const float* ebih_f  = (const float*)d_in[6];
  const float* ebhh_f  = (const float*)d_in[7];
  const float* eWih_b  = (const float*)d_in[8];
  const float* eWhh_b  = (const float*)d_in[9];
  const float* ebih_b  = (const float*)d_in[10];
  const float* ebhh_b  = (const float*)d_in[11];
  const float* dsW     = (const float*)d_in[12];
  const float* dsb     = (const float*)d_in[13];
  const float* dWih    = (const float*)d_in[14];
  const float* dWhh    = (const float*)d_in[15];
  const float* dbih    = (const float*)d_in[16];
  const float* dbhh    = (const float*)d_in[17];
  const float* aWenc   = (const float*)d_in[18];
  const float* abenc   = (const float*)d_in[19];
  const float* aWdec   = (const float*)d_in[20];
  const float* abdec   = (const float*)d_in[21];
  const float* av      = (const float*)d_in[22];
  const float* avb     = (const float*)d_in[23];
  const float* lW      = (const float*)d_in[24];
  const float* lb      = (const float*)d_in[25];
  float* dout = (float*)d_out;

  char* ws = (char*)d_ws;
  size_t off = 0;
  auto alloc = [&](size_t bytes) {
    void* p = ws + off;
    off += (bytes + 255) & ~(size_t)255;
    return p;
  };
  unsigned short* xb      = (unsigned short*)alloc((size_t)4096 * 256 * 2);
  unsigned short* xeb     = (unsigned short*)alloc((size_t)2016 * 256 * 2);
  unsigned short* xpb_f   = (unsigned short*)alloc((size_t)4096 * G3_ * 2);
  unsigned short* xpb_b   = (unsigned short*)alloc((size_t)4096 * G3_ * 2);
  unsigned short* encb    = (unsigned short*)alloc((size_t)4096 * D2H_ * 2);
  unsigned short* encpb   = (unsigned short*)alloc((size_t)4096 * 512 * 2);
  unsigned short* encWA   = (unsigned short*)alloc((size_t)4096 * G3_ * 2);
  uint32_t*       EWPd    = (uint32_t*)alloc((size_t)32 * 64 * 1536 * 4);
  float*          XE      = (float*)alloc((size_t)2016 * G3_ * 4);
  unsigned short* HAb     = (unsigned short*)alloc((size_t)2048 * G3_ * 2);
  unsigned short* lWb     = (unsigned short*)alloc((size_t)VO_ * G3_ * 2);
  uint32_t*       EWPf    = (uint32_t*)alloc((size_t)256 * 1536 * 4);
  uint32_t*       EWPb    = (uint32_t*)alloc((size_t)256 * 1536 * 4);
  uint32_t*       WHPd    = (uint32_t*)alloc((size_t)256 * 1536 * 4);
  uint32_t*       WDPd    = (uint32_t*)alloc((size_t)256 * 512 * 4);
  unsigned short* dWihb   = (unsigned short*)alloc((size_t)G3_ * 1280 * 2);
  unsigned short* aWencb  = (unsigned short*)alloc((size_t)512 * D2H_ * 2);
  unsigned short* eWihb_f = (unsigned short*)alloc((size_t)G3_ * 256 * 2);
  unsigned short* eWihb_b = (unsigned short*)alloc((size_t)G3_ * 256 * 2);

  // init + conversions
  k_init<<<192, 256, 0, stream>>>(HAb + (size_t)2016 * G3_);
  k_cvt_multi<<<1600, 256, 0, stream>>>(dWih, dWihb, aWenc, aWencb,
                                        eWih_f, eWihb_f, eWih_b, eWihb_b);
  k_cvt_tp<<<5120, 256, 0, stream>>>(eWhh_f, EWPf, eWhh_b, EWPb, dWhh, WHPd, aWdec, WDPd);
  k_cvt_bf16<<<24000, 256, 0, stream>>>(lW, lWb, VO_ * G3_ / 8);

  // embeddings
  k_gather_xb<<<512, 256, 0, stream>>>(inp, emb_inp, xb);
  k_gather_xeb<<<252, 256, 0, stream>>>(outi, emb_out, xeb);

  // xp = x @ eWih^T + ebih  (bf16 out)
  {
    dim3 g(12, 32);
    k_bgemm<1><<<g, 256, 0, stream>>>(xb, 256, eWihb_f, 256, ebih_f, xpb_f, G3_, 4096, G3_, 256);
    k_bgemm<1><<<g, 256, 0, stream>>>(xb, 256, eWihb_b, 256, ebih_b, xpb_b, G3_, 4096, G3_, 256);
  }

  // encoder
  k_encoder<<<64, 1024, 0, stream>>>(xpb_f, xpb_b, EWPf, ebhh_f, EWPb, ebhh_b, encb);

  // enc_proj (bias folded into decoder dp)
  {
    dim3 g(4, 32);
    k_bgemm<1><<<g, 256, 0, stream>>>(encb, D2H_, aWencb, D2H_, nullptr, encpb, 512, 4096, 512, D2H_);
  }
  // encWA = enc @ dWih_a^T  [4096][1536] bf16, then t-pair repack
  {
    dim3 g(12, 32);
    k_bgemm<1><<<g, 256, 0, stream>>>(encb, D2H_, dWihb + 256, 1280, nullptr, encWA, G3_, 4096, G3_, D2H_);
  }
  k_packT<<<12288, 256, 0, stream>>>(encWA, EWPd);

  // XE = xe @ dWih_e^T + dbih (f32 out)
  {
    dim3 g(12, 16);
    k_bgemm<0><<<g, 256, 0, stream>>>(xeb, 256, dWihb, 1280, dbih, XE, G3_, 2016, G3_, 256);
  }

  // decoder
  k_decoder<<<32, 1024, 0, stream>>>(inp, encb, encpb, XE, EWPd, WHPd, WDPd,
                                     dsW, dsb, dbhh, abdec, abenc, av, avb, HAb);

  // logits
  {
    dim3 g(250, 16);
    k_bgemm<3><<<g, 256, 0, stream>>>(HAb, G3_, lWb, G3_, lb, dout, 0, 2016, VO_, G3_);
  }
  k_first<<<4000, 256, 0, stream>>>(dout);
}